// Round 1
// baseline (488.100 us; speedup 1.0000x reference)
//
#include <hip/hip_runtime.h>
#include <hip/hip_bf16.h>
#include <math.h>

typedef __bf16 bf16_t;
typedef __bf16 bf16x8 __attribute__((ext_vector_type(8)));
typedef float f32x4 __attribute__((ext_vector_type(4)));

constexpr int Bc = 2, Tc = 2048, Cdim = 2048, Hc = 16, KVc = 4, HDc = 128;
constexpr int Mc = Bc * Tc;  // 4096

typedef const __attribute__((address_space(1))) void* as1_cptr;
typedef __attribute__((address_space(3))) void* as3_ptr;

__device__ __forceinline__ void gload_lds16(const bf16_t* g, bf16_t* l) {
  __builtin_amdgcn_global_load_lds((as1_cptr)(const void*)g, (as3_ptr)(void*)l, 16, 0, 0);
}

// ---------------- elementwise f32 -> bf16 (x) ----------------
__global__ void k_cvt_bf16(const float* __restrict__ in, bf16_t* __restrict__ out) {
  int i = (blockIdx.x * 256 + threadIdx.x) * 8;
  float4 a = *(const float4*)(in + i);
  float4 b = *(const float4*)(in + i + 4);
  bf16x8 v;
  v[0] = (bf16_t)a.x; v[1] = (bf16_t)a.y; v[2] = (bf16_t)a.z; v[3] = (bf16_t)a.w;
  v[4] = (bf16_t)b.x; v[5] = (bf16_t)b.y; v[6] = (bf16_t)b.z; v[7] = (bf16_t)b.w;
  *(bf16x8*)(out + i) = v;
}

// ---------------- W [K,N] f32 -> Wt [N,K] bf16 ----------------
__global__ void k_w_trans(const float* __restrict__ W, bf16_t* __restrict__ Wt,
                          int K, int N) {
  __shared__ alignas(16) bf16_t tile[64][72];  // pad 8 to break bank alignment
  const int k0 = blockIdx.x * 64, n0 = blockIdx.y * 64;
  const int t = threadIdx.x;
#pragma unroll
  for (int i = 0; i < 4; ++i) {
    int idx = t + i * 256;           // 0..1023
    int r = idx >> 4;                // k row 0..63
    int c4 = (idx & 15) * 4;         // n col group
    float4 v = *(const float4*)(W + (size_t)(k0 + r) * N + n0 + c4);
    tile[r][c4 + 0] = (bf16_t)v.x; tile[r][c4 + 1] = (bf16_t)v.y;
    tile[r][c4 + 2] = (bf16_t)v.z; tile[r][c4 + 3] = (bf16_t)v.w;
  }
  __syncthreads();
#pragma unroll
  for (int i = 0; i < 4; ++i) {
    int idx = t + i * 256;
    int n = idx >> 4;                // n row 0..63
    int kc = (idx & 15) * 4;         // k group
    alignas(8) bf16_t o[4];
#pragma unroll
    for (int j = 0; j < 4; ++j) o[j] = tile[kc + j][n];
    *(uint2*)(Wt + (size_t)(n0 + n) * K + k0 + kc) = *(uint2*)o;
  }
}

// ---------------- GEMM: C[M,N] = A[M,K] * Bt[N,K]^T, bf16 in, OutT out ----
// 128x128 block tile, BK=64, 4 waves (2x2), mfma 16x16x32 bf16.
// LDS layout XOR-swizzled: elem (r, k_local) at r*64 + ((k_local>>3)^(r&7))*8 + (k_local&7)
template <typename OutT>
__global__ __launch_bounds__(256, 2) void k_gemm_bt(
    const bf16_t* __restrict__ A, const bf16_t* __restrict__ Bt,
    OutT* __restrict__ Cout, int M, int N, int K) {
  __shared__ alignas(16) bf16_t Ash[128 * 64];
  __shared__ alignas(16) bf16_t Bsh[128 * 64];
  const int tid = threadIdx.x;
  const int wave = tid >> 6, lane = tid & 63;
  const int col = lane & 15, quad = lane >> 4;
  const int m0 = blockIdx.y * 128, n0 = blockIdx.x * 128;
  const int wr = wave >> 1, wc = wave & 1;

  f32x4 acc[4][4];
#pragma unroll
  for (int i = 0; i < 4; ++i)
#pragma unroll
    for (int j = 0; j < 4; ++j) acc[i][j] = f32x4{0.f, 0.f, 0.f, 0.f};

  const int lrow = lane >> 3;                 // 0..7 row within 8-row group
  const int lkc8 = (lane & 7) ^ lrow;         // swizzled k-chunk this lane fetches

  for (int k0 = 0; k0 < K; k0 += 64) {
    __syncthreads();
#pragma unroll
    for (int i = 0; i < 4; ++i) {
      const int rb = wave * 32 + i * 8;       // 8-row group base
      gload_lds16(A + (size_t)(m0 + rb + lrow) * K + k0 + lkc8 * 8, Ash + rb * 64);
      gload_lds16(Bt + (size_t)(n0 + rb + lrow) * K + k0 + lkc8 * 8, Bsh + rb * 64);
    }
    __syncthreads();
#pragma unroll
    for (int kc = 0; kc < 2; ++kc) {
      bf16x8 af[4], bfr[4];
#pragma unroll
      for (int mt = 0; mt < 4; ++mt) {
        const int m = wr * 64 + mt * 16 + col;
        const int slot = (kc * 4 + quad) ^ (m & 7);
        af[mt] = *(const bf16x8*)(Ash + m * 64 + slot * 8);
      }
#pragma unroll
      for (int nt = 0; nt < 4; ++nt) {
        const int n = wc * 64 + nt * 16 + col;
        const int slot = (kc * 4 + quad) ^ (n & 7);
        bfr[nt] = *(const bf16x8*)(Bsh + n * 64 + slot * 8);
      }
#pragma unroll
      for (int mt = 0; mt < 4; ++mt)
#pragma unroll
        for (int nt = 0; nt < 4; ++nt)
          acc[mt][nt] = __builtin_amdgcn_mfma_f32_16x16x32_bf16(
              af[mt], bfr[nt], acc[mt][nt], 0, 0, 0);
    }
  }
#pragma unroll
  for (int mt = 0; mt < 4; ++mt)
#pragma unroll
    for (int i = 0; i < 4; ++i) {
      const int row = m0 + wr * 64 + mt * 16 + quad * 4 + i;
#pragma unroll
      for (int nt = 0; nt < 4; ++nt)
        Cout[(size_t)row * N + n0 + wc * 64 + nt * 16 + col] = (OutT)acc[mt][nt][i];
    }
}

// ---------------- RoPE + head-major repack -------------------
// in:  [B, T, NH, HD] bf16   out: [B, NH, T, HD] bf16
__global__ void k_rope(const bf16_t* __restrict__ in, const float* __restrict__ cs,
                       const float* __restrict__ sn, bf16_t* __restrict__ out, int NH) {
  const int idx = blockIdx.x * 256 + threadIdx.x;
  const int d = idx & 63;
  const int h = (idx >> 6) % NH;
  const int bt = idx / (64 * NH);
  const int t = bt & (Tc - 1);
  const int b = bt >> 11;
  const size_t bi = ((size_t)(b * Tc + t) * NH + h) * HDc;
  const float x0 = (float)in[bi + d];
  const float x1 = (float)in[bi + d + 64];
  const float c0 = cs[t * HDc + d], c1 = cs[t * HDc + d + 64];
  const float s0 = sn[t * HDc + d], s1 = sn[t * HDc + d + 64];
  const size_t bo = ((size_t)(b * NH + h) * Tc + t) * HDc;
  out[bo + d]      = (bf16_t)(x0 * c0 - x1 * s0);
  out[bo + d + 64] = (bf16_t)(x1 * c1 + x0 * s1);
}

// ---------------- V repack: [B,T,KV,HD] -> [B,KV,HD,T] -------
__global__ void k_vtrans(const bf16_t* __restrict__ v, bf16_t* __restrict__ vt) {
  __shared__ alignas(16) bf16_t tile[64][136];  // 64 t-rows x 128 d, pad 8
  const int t0 = blockIdx.x * 64;
  const int kv = blockIdx.y, b = blockIdx.z;
  const int tid = threadIdx.x;
#pragma unroll
  for (int i = 0; i < 4; ++i) {
    int idx = tid + i * 256;
    int r = idx >> 4;        // t row
    int ch = idx & 15;       // 16B chunk over d
    const bf16_t* gp = v + ((size_t)((b * Tc + t0 + r) * KVc + kv)) * HDc + ch * 8;
    *(uint4*)&tile[r][ch * 8] = *(const uint4*)gp;
  }
  __syncthreads();
#pragma unroll
  for (int i = 0; i < 4; ++i) {
    int idx = tid + i * 256;
    int d = idx >> 3;        // 0..127
    int tc = idx & 7;        // t chunk of 8
    alignas(16) bf16_t o[8];
#pragma unroll
    for (int j = 0; j < 8; ++j) o[j] = tile[tc * 8 + j][d];
    bf16_t* gp = vt + ((size_t)(b * KVc + kv) * HDc + d) * Tc + t0 + tc * 8;
    *(uint4*)gp = *(uint4*)o;
  }
}

// ---------------- Flash attention (causal, GQA) --------------
// Qp [B,H,T,HD], Kp [B,KV,T,HD], Vt [B,KV,HD,T] -> Oout [B,T,H*HD]
__global__ __launch_bounds__(256, 2) void k_attn(
    const bf16_t* __restrict__ Qp, const bf16_t* __restrict__ Kp,
    const bf16_t* __restrict__ Vt, bf16_t* __restrict__ Oout) {
  constexpr float scale = 0.08838834764831845f;  // 1/sqrt(128)
  __shared__ alignas(16) bf16_t Ksh[32 * 128];   // swizzled rows of 16 slots
  __shared__ alignas(16) bf16_t Vsh[128 * 32];   // swizzled rows of 4 slots
  __shared__ alignas(16) bf16_t Psh[4][16 * 40]; // per-wave P 16x32, rows padded to 40

  const int qb = blockIdx.x, h = blockIdx.y, b = blockIdx.z;
  const int kvh = h >> 2;  // REP = 4
  const int tid = threadIdx.x, wave = tid >> 6, lane = tid & 63;
  const int col = lane & 15, quad = lane >> 4;
  const int q0 = qb * 64 + wave * 16;

  bf16x8 qf[4];
  const bf16_t* qbase = Qp + ((size_t)(b * Hc + h) * Tc + q0 + col) * HDc;
#pragma unroll
  for (int kc = 0; kc < 4; ++kc) qf[kc] = *(const bf16x8*)(qbase + kc * 32 + quad * 8);

  f32x4 o_acc[8];
#pragma unroll
  for (int nb = 0; nb < 8; ++nb) o_acc[nb] = f32x4{0.f, 0.f, 0.f, 0.f};
  float m_i[4] = {-INFINITY, -INFINITY, -INFINITY, -INFINITY};
  float l_i[4] = {0.f, 0.f, 0.f, 0.f};

  const bf16_t* Kb = Kp + (size_t)(b * KVc + kvh) * Tc * HDc;
  const bf16_t* Vb = Vt + (size_t)(b * KVc + kvh) * HDc * Tc;
  const int nkt = qb * 2 + 2;

  for (int kt = 0; kt < nkt; ++kt) {
    const int kbase = kt * 32;
    __syncthreads();
#pragma unroll
    for (int i = 0; i < 2; ++i) {
      // K tile: 4 rows x 16 slots per instruction
      const int rb = wave * 8 + i * 4;
      const int r = rb + (lane >> 4);
      const int kc8 = (lane & 15) ^ (r & 7);
      gload_lds16(Kb + (size_t)(kbase + r) * HDc + kc8 * 8, Ksh + rb * 128);
      // V tile: 16 d-rows x 4 slots per instruction
      const int d0 = wave * 32 + i * 16;
      const int d = d0 + (lane >> 2);
      const int tc8 = (lane & 3) ^ (d & 3) ^ ((d >> 2) & 3);
      gload_lds16(Vb + (size_t)d * Tc + kbase + tc8 * 8, Vsh + d0 * 32);
    }
    __syncthreads();

    // S = Q K^T  (two 16-col blocks of a 16x32 tile)
    f32x4 s0 = f32x4{0.f, 0.f, 0.f, 0.f}, s1 = s0;
#pragma unroll
    for (int kc = 0; kc < 4; ++kc) {
      {
        const int r = col;
        const int slot = (kc * 4 + quad) ^ (r & 7);
        bf16x8 kf = *(const bf16x8*)(Ksh + r * 128 + slot * 8);
        s0 = __builtin_amdgcn_mfma_f32_16x16x32_bf16(qf[kc], kf, s0, 0, 0, 0);
      }
      {
        const int r = 16 + col;
        const int slot = (kc * 4 + quad) ^ (r & 7);
        bf16x8 kf = *(const bf16x8*)(Ksh + r * 128 + slot * 8);
        s1 = __builtin_amdgcn_mfma_f32_16x16x32_bf16(qf[kc], kf, s1, 0, 0, 0);
      }
    }

    // mask + online softmax (C layout: row = quad*4+i, col = lane&15)
    float p0[4], p1[4];
    const int kc0 = kbase + col, kc1 = kbase + 16 + col;
#pragma unroll
    for (int i = 0; i < 4; ++i) {
      const int qrow = q0 + quad * 4 + i;
      float a = s0[i] * scale, c = s1[i] * scale;
      if (kc0 > qrow) a = -INFINITY;
      if (kc1 > qrow) c = -INFINITY;
      float mx = fmaxf(a, c);
      mx = fmaxf(mx, __shfl_xor(mx, 1));
      mx = fmaxf(mx, __shfl_xor(mx, 2));
      mx = fmaxf(mx, __shfl_xor(mx, 4));
      mx = fmaxf(mx, __shfl_xor(mx, 8));
      const float m_new = fmaxf(m_i[i], mx);
      const float alpha = __expf(m_i[i] - m_new);
      const float e0 = __expf(a - m_new);
      const float e1 = __expf(c - m_new);
      p0[i] = e0; p1[i] = e1;
      float rs = e0 + e1;
      rs += __shfl_xor(rs, 1);
      rs += __shfl_xor(rs, 2);
      rs += __shfl_xor(rs, 4);
      rs += __shfl_xor(rs, 8);
      l_i[i] = l_i[i] * alpha + rs;
      m_i[i] = m_new;
#pragma unroll
      for (int nb = 0; nb < 8; ++nb) o_acc[nb][i] *= alpha;
    }

    // P: C-layout -> A-layout via per-wave LDS round trip
    bf16_t* pw = &Psh[wave][0];
#pragma unroll
    for (int i = 0; i < 4; ++i) {
      pw[(quad * 4 + i) * 40 + col]      = (bf16_t)p0[i];
      pw[(quad * 4 + i) * 40 + 16 + col] = (bf16_t)p1[i];
    }
    asm volatile("s_waitcnt lgkmcnt(0)" ::: "memory");
    const bf16x8 pf = *(const bf16x8*)(pw + col * 40 + quad * 8);

    // O += P V
#pragma unroll
    for (int nb = 0; nb < 8; ++nb) {
      const int d = nb * 16 + col;
      const int slot = quad ^ (d & 3) ^ ((d >> 2) & 3);
      bf16x8 vf = *(const bf16x8*)(Vsh + d * 32 + slot * 8);
      o_acc[nb] = __builtin_amdgcn_mfma_f32_16x16x32_bf16(pf, vf, o_acc[nb], 0, 0, 0);
    }
  }

#pragma unroll
  for (int i = 0; i < 4; ++i) {
    const float inv = 1.0f / l_i[i];
    const int qrow = q0 + quad * 4 + i;
    bf16_t* op = Oout + ((size_t)(b * Tc) + qrow) * (Hc * HDc) + h * HDc;
#pragma unroll
    for (int nb = 0; nb < 8; ++nb) op[nb * 16 + col] = (bf16_t)(o_acc[nb][i] * inv);
  }
}

// ---------------- launch ----------------
extern "C" void kernel_launch(void* const* d_in, const int* in_sizes, int n_in,
                              void* d_out, int out_size, void* d_ws, size_t ws_size,
                              hipStream_t stream) {
  (void)in_sizes; (void)n_in; (void)out_size; (void)ws_size;
  const float* x    = (const float*)d_in[0];
  const float* cosT = (const float*)d_in[1];
  const float* sinT = (const float*)d_in[2];
  const float* Wq   = (const float*)d_in[3];
  const float* Wk   = (const float*)d_in[4];
  const float* Wv   = (const float*)d_in[5];
  const float* Wo   = (const float*)d_in[6];
  float* out = (float*)d_out;

  char* ws = (char*)d_ws;
  size_t off = 0;
  auto take = [&](size_t bytes) { char* p = ws + off; off += (bytes + 255) & ~(size_t)255; return p; };

  bf16_t* xb   = (bf16_t*)take((size_t)Mc * Cdim * 2);        // also reused as Qp
  bf16_t* Wqt  = (bf16_t*)take((size_t)Cdim * (Hc * HDc) * 2);
  bf16_t* Wkt  = (bf16_t*)take((size_t)Cdim * (KVc * HDc) * 2);
  bf16_t* Wvt  = (bf16_t*)take((size_t)Cdim * (KVc * HDc) * 2);
  bf16_t* Wot  = (bf16_t*)take((size_t)(Hc * HDc) * Cdim * 2);
  bf16_t* qlin = (bf16_t*)take((size_t)Mc * (Hc * HDc) * 2);  // also reused as attn_out
  bf16_t* klin = (bf16_t*)take((size_t)Mc * (KVc * HDc) * 2);
  bf16_t* vlin = (bf16_t*)take((size_t)Mc * (KVc * HDc) * 2);
  bf16_t* Kp   = (bf16_t*)take((size_t)Mc * (KVc * HDc) * 2);
  bf16_t* Vt   = (bf16_t*)take((size_t)Mc * (KVc * HDc) * 2);
  bf16_t* Qp   = xb;    // alias: xb dead after the 3 projection GEMMs
  bf16_t* attn = qlin;  // alias: qlin dead after rope_q

  // 1. convert x
  k_cvt_bf16<<<dim3((Mc * Cdim) / 2048), dim3(256), 0, stream>>>(x, xb);
  // 2. transpose-convert weights to [N,K] bf16
  k_w_trans<<<dim3(Cdim / 64, (Hc * HDc) / 64), dim3(256), 0, stream>>>(Wq, Wqt, Cdim, Hc * HDc);
  k_w_trans<<<dim3(Cdim / 64, (KVc * HDc) / 64), dim3(256), 0, stream>>>(Wk, Wkt, Cdim, KVc * HDc);
  k_w_trans<<<dim3(Cdim / 64, (KVc * HDc) / 64), dim3(256), 0, stream>>>(Wv, Wvt, Cdim, KVc * HDc);
  k_w_trans<<<dim3((Hc * HDc) / 64, Cdim / 64), dim3(256), 0, stream>>>(Wo, Wot, Hc * HDc, Cdim);
  // 3. projection GEMMs
  k_gemm_bt<bf16_t><<<dim3((Hc * HDc) / 128, Mc / 128), dim3(256), 0, stream>>>(
      xb, Wqt, qlin, Mc, Hc * HDc, Cdim);
  k_gemm_bt<bf16_t><<<dim3((KVc * HDc) / 128, Mc / 128), dim3(256), 0, stream>>>(
      xb, Wkt, klin, Mc, KVc * HDc, Cdim);
  k_gemm_bt<bf16_t><<<dim3((KVc * HDc) / 128, Mc / 128), dim3(256), 0, stream>>>(
      xb, Wvt, vlin, Mc, KVc * HDc, Cdim);
  // 4. RoPE + repack (q overwrites xb region — safe, GEMMs done)
  k_rope<<<dim3((Bc * Tc * Hc * 64) / 256), dim3(256), 0, stream>>>(qlin, cosT, sinT, Qp, Hc);
  k_rope<<<dim3((Bc * Tc * KVc * 64) / 256), dim3(256), 0, stream>>>(klin, cosT, sinT, Kp, KVc);
  // 5. V transpose
  k_vtrans<<<dim3(Tc / 64, KVc, Bc), dim3(256), 0, stream>>>(vlin, Vt);
  // 6. attention (writes into qlin region — safe, rope_q done)
  k_attn<<<dim3(Tc / 64, Hc, Bc), dim3(256), 0, stream>>>(Qp, Kp, Vt, attn);
  // 7. output projection, fp32 out
  k_gemm_bt<float><<<dim3(Cdim / 128, Mc / 128), dim3(256), 0, stream>>>(
      attn, Wot, out, Mc, Cdim, Hc * HDc);
}

// Round 2
// 361.820 us; speedup vs baseline: 1.3490x; 1.3490x over previous
//
#include <hip/hip_runtime.h>
#include <hip/hip_bf16.h>
#include <math.h>

typedef __bf16 bf16_t;
typedef __bf16 bf16x8 __attribute__((ext_vector_type(8)));
typedef float f32x4 __attribute__((ext_vector_type(4)));

constexpr int Bc = 2, Tc = 2048, Cdim = 2048, Hc = 16, KVc = 4, HDc = 128;
constexpr int Mc = Bc * Tc;      // 4096
constexpr int Nqkv = 3072;       // fused projection width: 2048 Q + 512 K + 512 V

typedef const __attribute__((address_space(1))) void* as1_cptr;
typedef __attribute__((address_space(3))) void* as3_ptr;

__device__ __forceinline__ void gload_lds16(const bf16_t* g, bf16_t* l) {
  __builtin_amdgcn_global_load_lds((as1_cptr)(const void*)g, (as3_ptr)(void*)l, 16, 0, 0);
}

// ---------------- elementwise f32 -> bf16 (x) ----------------
__global__ void k_cvt_bf16(const float* __restrict__ in, bf16_t* __restrict__ out) {
  int i = (blockIdx.x * 256 + threadIdx.x) * 8;
  float4 a = *(const float4*)(in + i);
  float4 b = *(const float4*)(in + i + 4);
  bf16x8 v;
  v[0] = (bf16_t)a.x; v[1] = (bf16_t)a.y; v[2] = (bf16_t)a.z; v[3] = (bf16_t)a.w;
  v[4] = (bf16_t)b.x; v[5] = (bf16_t)b.y; v[6] = (bf16_t)b.z; v[7] = (bf16_t)b.w;
  *(bf16x8*)(out + i) = v;
}

// ---------------- W [K,N] f32 -> Wt [N,K] bf16 ----------------
__global__ void k_w_trans(const float* __restrict__ W, bf16_t* __restrict__ Wt,
                          int K, int N) {
  __shared__ alignas(16) bf16_t tile[64][72];
  const int k0 = blockIdx.x * 64, n0 = blockIdx.y * 64;
  const int t = threadIdx.x;
#pragma unroll
  for (int i = 0; i < 4; ++i) {
    int idx = t + i * 256;
    int r = idx >> 4;
    int c4 = (idx & 15) * 4;
    float4 v = *(const float4*)(W + (size_t)(k0 + r) * N + n0 + c4);
    tile[r][c4 + 0] = (bf16_t)v.x; tile[r][c4 + 1] = (bf16_t)v.y;
    tile[r][c4 + 2] = (bf16_t)v.z; tile[r][c4 + 3] = (bf16_t)v.w;
  }
  __syncthreads();
#pragma unroll
  for (int i = 0; i < 4; ++i) {
    int idx = t + i * 256;
    int n = idx >> 4;
    int kc = (idx & 15) * 4;
    alignas(8) bf16_t o[4];
#pragma unroll
    for (int j = 0; j < 4; ++j) o[j] = tile[kc + j][n];
    *(uint2*)(Wt + (size_t)(n0 + n) * K + k0 + kc) = *(uint2*)o;
  }
}

// ---------------- GEMM: C[M,N] = A[M,K] * Bt[N,K]^T ----------
template <typename OutT>
__global__ __launch_bounds__(256, 2) void k_gemm_bt(
    const bf16_t* __restrict__ A, const bf16_t* __restrict__ Bt,
    OutT* __restrict__ Cout, int M, int N, int K) {
  __shared__ alignas(16) bf16_t Ash[128 * 64];
  __shared__ alignas(16) bf16_t Bsh[128 * 64];
  const int tid = threadIdx.x;
  const int wave = tid >> 6, lane = tid & 63;
  const int col = lane & 15, quad = lane >> 4;
  const int m0 = blockIdx.y * 128, n0 = blockIdx.x * 128;
  const int wr = wave >> 1, wc = wave & 1;

  f32x4 acc[4][4];
#pragma unroll
  for (int i = 0; i < 4; ++i)
#pragma unroll
    for (int j = 0; j < 4; ++j) acc[i][j] = f32x4{0.f, 0.f, 0.f, 0.f};

  const int lrow = lane >> 3;
  const int lkc8 = (lane & 7) ^ lrow;

  for (int k0 = 0; k0 < K; k0 += 64) {
    __syncthreads();
#pragma unroll
    for (int i = 0; i < 4; ++i) {
      const int rb = wave * 32 + i * 8;
      gload_lds16(A + (size_t)(m0 + rb + lrow) * K + k0 + lkc8 * 8, Ash + rb * 64);
      gload_lds16(Bt + (size_t)(n0 + rb + lrow) * K + k0 + lkc8 * 8, Bsh + rb * 64);
    }
    __syncthreads();
#pragma unroll
    for (int kc = 0; kc < 2; ++kc) {
      bf16x8 af[4], bfr[4];
#pragma unroll
      for (int mt = 0; mt < 4; ++mt) {
        const int m = wr * 64 + mt * 16 + col;
        const int slot = (kc * 4 + quad) ^ (m & 7);
        af[mt] = *(const bf16x8*)(Ash + m * 64 + slot * 8);
      }
#pragma unroll
      for (int nt = 0; nt < 4; ++nt) {
        const int n = wc * 64 + nt * 16 + col;
        const int slot = (kc * 4 + quad) ^ (n & 7);
        bfr[nt] = *(const bf16x8*)(Bsh + n * 64 + slot * 8);
      }
#pragma unroll
      for (int mt = 0; mt < 4; ++mt)
#pragma unroll
        for (int nt = 0; nt < 4; ++nt)
          acc[mt][nt] = __builtin_amdgcn_mfma_f32_16x16x32_bf16(
              af[mt], bfr[nt], acc[mt][nt], 0, 0, 0);
    }
  }
#pragma unroll
  for (int mt = 0; mt < 4; ++mt)
#pragma unroll
    for (int i = 0; i < 4; ++i) {
      const int row = m0 + wr * 64 + mt * 16 + quad * 4 + i;
#pragma unroll
      for (int nt = 0; nt < 4; ++nt)
        Cout[(size_t)row * N + n0 + wc * 64 + nt * 16 + col] = (OutT)acc[mt][nt][i];
    }
}

// ---------------- RoPE + head-major repack -------------------
// in: fused rows [B*T, in_stride], head block at col_off + h*HD
// out: [B, NH, T, HD] bf16
__global__ void k_rope(const bf16_t* __restrict__ in, const float* __restrict__ cs,
                       const float* __restrict__ sn, bf16_t* __restrict__ out,
                       int NH, int in_stride, int col_off) {
  const int idx = blockIdx.x * 256 + threadIdx.x;
  const int d = idx & 63;
  const int h = (idx >> 6) % NH;
  const int bt = idx / (64 * NH);
  const int t = bt & (Tc - 1);
  const int b = bt >> 11;
  const size_t bi = (size_t)(b * Tc + t) * in_stride + col_off + h * HDc;
  const float x0 = (float)in[bi + d];
  const float x1 = (float)in[bi + d + 64];
  const float c0 = cs[t * HDc + d], c1 = cs[t * HDc + d + 64];
  const float s0 = sn[t * HDc + d], s1 = sn[t * HDc + d + 64];
  const size_t bo = ((size_t)(b * NH + h) * Tc + t) * HDc;
  out[bo + d]      = (bf16_t)(x0 * c0 - x1 * s0);
  out[bo + d + 64] = (bf16_t)(x1 * c1 + x0 * s1);
}

// ---------------- V repack: fused rows -> [B,KV,HD,T] --------
__global__ void k_vtrans(const bf16_t* __restrict__ v, bf16_t* __restrict__ vt,
                         int in_stride, int col_off) {
  __shared__ alignas(16) bf16_t tile[64][136];
  const int t0 = blockIdx.x * 64;
  const int kv = blockIdx.y, b = blockIdx.z;
  const int tid = threadIdx.x;
#pragma unroll
  for (int i = 0; i < 4; ++i) {
    int idx = tid + i * 256;
    int r = idx >> 4;
    int ch = idx & 15;
    const bf16_t* gp = v + (size_t)(b * Tc + t0 + r) * in_stride + col_off + kv * HDc + ch * 8;
    *(uint4*)&tile[r][ch * 8] = *(const uint4*)gp;
  }
  __syncthreads();
#pragma unroll
  for (int i = 0; i < 4; ++i) {
    int idx = tid + i * 256;
    int d = idx >> 3;
    int tc = idx & 7;
    alignas(16) bf16_t o[8];
#pragma unroll
    for (int j = 0; j < 8; ++j) o[j] = tile[tc * 8 + j][d];
    bf16_t* gp = vt + ((size_t)(b * KVc + kv) * HDc + d) * Tc + t0 + tc * 8;
    *(uint4*)gp = *(uint4*)o;
  }
}

// ---------------- Flash attention v2 (balanced, KV=64) -------
// Qp [B,H,T,HD], Kp [B,KV,T,HD], Vt [B,KV,HD,T] -> Oout [B,T,H*HD]
// Block = (pair i, h, b); processes qb = 31-i then qb = i  => 33 KV-tiles/block.
__global__ __launch_bounds__(256, 2) void k_attn(
    const bf16_t* __restrict__ Qp, const bf16_t* __restrict__ Kp,
    const bf16_t* __restrict__ Vt, bf16_t* __restrict__ Oout) {
  constexpr float scale = 0.08838834764831845f;  // 1/sqrt(128)
  __shared__ alignas(16) bf16_t Ksh[64 * 128];   // row stride 128, 16 slots swizzled ^(r&7)
  __shared__ alignas(16) bf16_t Vsh[128 * 64];   // row stride 64, 8 slots swizzled ^(d&7)
  __shared__ alignas(16) bf16_t Psh[4][16 * 72]; // per-wave P 16x64, stride 72

  const int i2 = blockIdx.x, h = blockIdx.y, b = blockIdx.z;
  const int kvh = h >> 2;  // REP = 4
  const int tid = threadIdx.x, wave = tid >> 6, lane = tid & 63;
  const int col = lane & 15, quad = lane >> 4;

  const bf16_t* Kb = Kp + (size_t)(b * KVc + kvh) * Tc * HDc;
  const bf16_t* Vb = Vt + (size_t)(b * KVc + kvh) * HDc * Tc;

  int qbs[2] = {31 - i2, i2};

  for (int pass = 0; pass < 2; ++pass) {
    const int qb = qbs[pass];
    const int q0 = qb * 64 + wave * 16;

    bf16x8 qf[4];
    const bf16_t* qbase = Qp + ((size_t)(b * Hc + h) * Tc + q0 + col) * HDc;
#pragma unroll
    for (int kc = 0; kc < 4; ++kc) qf[kc] = *(const bf16x8*)(qbase + kc * 32 + quad * 8);

    f32x4 o_acc[8];
#pragma unroll
    for (int nb = 0; nb < 8; ++nb) o_acc[nb] = f32x4{0.f, 0.f, 0.f, 0.f};
    float m_i[4] = {-INFINITY, -INFINITY, -INFINITY, -INFINITY};
    float l_i[4] = {0.f, 0.f, 0.f, 0.f};

#pragma unroll 1
    for (int kt = 0; kt <= qb; ++kt) {
      const int kbase = kt * 64;
      const bool diag = (kt == qb);
      __syncthreads();
#pragma unroll
      for (int i = 0; i < 4; ++i) {
        // K tile: 64 rows x 128; instr covers 4 rows x 16 slots
        const int rb = wave * 16 + i * 4;
        const int r = rb + (lane >> 4);
        const int kc8 = (lane & 15) ^ (r & 7);
        gload_lds16(Kb + (size_t)(kbase + r) * HDc + kc8 * 8, Ksh + rb * 128);
        // V tile: 128 d-rows x 64; instr covers 8 rows x 8 slots
        const int db = wave * 32 + i * 8;
        const int d = db + (lane >> 3);
        const int tc8 = (lane & 7) ^ (d & 7);
        gload_lds16(Vb + (size_t)d * Tc + kbase + tc8 * 8, Vsh + db * 64);
      }
      __syncthreads();

      // S = Q K^T : 16 q-rows x 64 kv  (4 16-col subtiles)
      f32x4 st[4];
#pragma unroll
      for (int tb = 0; tb < 4; ++tb) st[tb] = f32x4{0.f, 0.f, 0.f, 0.f};
#pragma unroll
      for (int kc = 0; kc < 4; ++kc)
#pragma unroll
        for (int tb = 0; tb < 4; ++tb) {
          const int r = tb * 16 + col;
          const int slot = (kc * 4 + quad) ^ (r & 7);
          bf16x8 kf = *(const bf16x8*)(Ksh + r * 128 + slot * 8);
          st[tb] = __builtin_amdgcn_mfma_f32_16x16x32_bf16(qf[kc], kf, st[tb], 0, 0, 0);
        }

      // online softmax (C layout: row = quad*4+i, col = lane&15)
      bf16_t* pw = &Psh[wave][0];
      const int rowthr = wave * 16 + quad * 4;
#pragma unroll
      for (int i = 0; i < 4; ++i) {
        float v0 = st[0][i] * scale, v1 = st[1][i] * scale;
        float v2 = st[2][i] * scale, v3 = st[3][i] * scale;
        if (diag) {
          const int thr = rowthr + i;
          if (col      > thr) v0 = -INFINITY;
          if (16 + col > thr) v1 = -INFINITY;
          if (32 + col > thr) v2 = -INFINITY;
          if (48 + col > thr) v3 = -INFINITY;
        }
        float mx = fmaxf(fmaxf(v0, v1), fmaxf(v2, v3));
        mx = fmaxf(mx, __shfl_xor(mx, 1));
        mx = fmaxf(mx, __shfl_xor(mx, 2));
        mx = fmaxf(mx, __shfl_xor(mx, 4));
        mx = fmaxf(mx, __shfl_xor(mx, 8));
        const float m_new = fmaxf(m_i[i], mx);
        const float alpha = __expf(m_i[i] - m_new);
        const float e0 = __expf(v0 - m_new), e1 = __expf(v1 - m_new);
        const float e2 = __expf(v2 - m_new), e3 = __expf(v3 - m_new);
        float rs = (e0 + e1) + (e2 + e3);
        rs += __shfl_xor(rs, 1);
        rs += __shfl_xor(rs, 2);
        rs += __shfl_xor(rs, 4);
        rs += __shfl_xor(rs, 8);
        l_i[i] = l_i[i] * alpha + rs;
        m_i[i] = m_new;
        const int prow = (quad * 4 + i) * 72;
        pw[prow + col]      = (bf16_t)e0;
        pw[prow + 16 + col] = (bf16_t)e1;
        pw[prow + 32 + col] = (bf16_t)e2;
        pw[prow + 48 + col] = (bf16_t)e3;
#pragma unroll
        for (int nb = 0; nb < 8; ++nb) o_acc[nb][i] *= alpha;
      }
      asm volatile("s_waitcnt lgkmcnt(0)" ::: "memory");

      // O += P V
#pragma unroll
      for (int kc = 0; kc < 2; ++kc) {
        const bf16x8 pf = *(const bf16x8*)(pw + col * 72 + kc * 32 + quad * 8);
#pragma unroll
        for (int nb = 0; nb < 8; ++nb) {
          const int d = nb * 16 + col;
          const int slot = (kc * 4 + quad) ^ (d & 7);
          bf16x8 vf = *(const bf16x8*)(Vsh + d * 64 + slot * 8);
          o_acc[nb] = __builtin_amdgcn_mfma_f32_16x16x32_bf16(pf, vf, o_acc[nb], 0, 0, 0);
        }
      }
    }

#pragma unroll
    for (int i = 0; i < 4; ++i) {
      const float inv = 1.0f / l_i[i];
      const int qrow = q0 + quad * 4 + i;
      bf16_t* op = Oout + ((size_t)(b * Tc) + qrow) * (Hc * HDc) + h * HDc;
#pragma unroll
      for (int nb = 0; nb < 8; ++nb) op[nb * 16 + col] = (bf16_t)(o_acc[nb][i] * inv);
    }
  }
}

// ---------------- launch ----------------
extern "C" void kernel_launch(void* const* d_in, const int* in_sizes, int n_in,
                              void* d_out, int out_size, void* d_ws, size_t ws_size,
                              hipStream_t stream) {
  (void)in_sizes; (void)n_in; (void)out_size; (void)ws_size;
  const float* x    = (const float*)d_in[0];
  const float* cosT = (const float*)d_in[1];
  const float* sinT = (const float*)d_in[2];
  const float* Wq   = (const float*)d_in[3];
  const float* Wk   = (const float*)d_in[4];
  const float* Wv   = (const float*)d_in[5];
  const float* Wo   = (const float*)d_in[6];
  float* out = (float*)d_out;

  char* ws = (char*)d_ws;
  size_t off = 0;
  auto take = [&](size_t bytes) { char* p = ws + off; off += (bytes + 255) & ~(size_t)255; return p; };

  bf16_t* xb    = (bf16_t*)take((size_t)Mc * Cdim * 2);      // reused as Qp after proj
  bf16_t* Wqkvt = (bf16_t*)take((size_t)Nqkv * Cdim * 2);    // [3072][2048]
  bf16_t* Wot   = (bf16_t*)take((size_t)Cdim * (Hc * HDc) * 2);
  bf16_t* qkv   = (bf16_t*)take((size_t)Mc * Nqkv * 2);      // reused as attn out
  bf16_t* Kp    = (bf16_t*)take((size_t)Mc * (KVc * HDc) * 2);
  bf16_t* Vt    = (bf16_t*)take((size_t)Mc * (KVc * HDc) * 2);
  bf16_t* Wqt = Wqkvt;
  bf16_t* Wkt = Wqkvt + (size_t)2048 * Cdim;
  bf16_t* Wvt = Wqkvt + (size_t)2560 * Cdim;
  bf16_t* Qp   = xb;
  bf16_t* attn = qkv;

  // 1. convert x
  k_cvt_bf16<<<dim3((Mc * Cdim) / 2048), dim3(256), 0, stream>>>(x, xb);
  // 2. transpose-convert weights into fused [3072][2048] (+ Wot)
  k_w_trans<<<dim3(Cdim / 64, 2048 / 64), dim3(256), 0, stream>>>(Wq, Wqt, Cdim, 2048);
  k_w_trans<<<dim3(Cdim / 64, 512 / 64), dim3(256), 0, stream>>>(Wk, Wkt, Cdim, 512);
  k_w_trans<<<dim3(Cdim / 64, 512 / 64), dim3(256), 0, stream>>>(Wv, Wvt, Cdim, 512);
  k_w_trans<<<dim3((Hc * HDc) / 64, Cdim / 64), dim3(256), 0, stream>>>(Wo, Wot, Hc * HDc, Cdim);
  // 3. fused QKV projection: [4096 x 3072]
  k_gemm_bt<bf16_t><<<dim3(Nqkv / 128, Mc / 128), dim3(256), 0, stream>>>(
      xb, Wqkvt, qkv, Mc, Nqkv, Cdim);
  // 4. RoPE + repack (Q overwrites xb — safe, proj done)
  k_rope<<<dim3((Bc * Tc * Hc * 64) / 256), dim3(256), 0, stream>>>(
      qkv, cosT, sinT, Qp, Hc, Nqkv, 0);
  k_rope<<<dim3((Bc * Tc * KVc * 64) / 256), dim3(256), 0, stream>>>(
      qkv, cosT, sinT, Kp, KVc, Nqkv, 2048);
  // 5. V transpose
  k_vtrans<<<dim3(Tc / 64, KVc, Bc), dim3(256), 0, stream>>>(qkv, Vt, Nqkv, 2560);
  // 6. attention (balanced pairs; writes into qkv region — safe)
  k_attn<<<dim3(16, Hc, Bc), dim3(256), 0, stream>>>(Qp, Kp, Vt, attn);
  // 7. output projection, fp32 out
  k_gemm_bt<float><<<dim3(Cdim / 128, Mc / 128), dim3(256), 0, stream>>>(
      attn, Wot, out, Mc, Cdim, Hc * HDc);
}